// Round 21
// baseline (107.384 us; speedup 1.0000x reference)
//
#include <hip/hip_runtime.h>
#include <hip/hip_bf16.h>

typedef __attribute__((ext_vector_type(4)))  float f32x4;
typedef __attribute__((ext_vector_type(16))) float f32x16;
typedef __attribute__((ext_vector_type(8)))  short s16x8;
typedef __attribute__((ext_vector_type(4)))  unsigned int u32x4;

using bf16 = __hip_bfloat16;

#define DIMC   1024
#define NH     16
#define HD     64
#define SEQ    2048
#define NB     2
#define NROWS  (NB*SEQ)   // 4096
#define NQKV   1152       // 1024 q + 64 k + 64 v
#define QSCL   0.18033688f   // 1/sqrt(64) * log2(e), folded into Q at epilogue

// ---- cross-lane / fast-math helpers (gfx950) ----
static __device__ __forceinline__ unsigned cvt_pk_bf16(float lo, float hi) {
  unsigned r;
  asm("v_cvt_pk_bf16_f32 %0, %1, %2" : "=v"(r) : "v"(lo), "v"(hi));
  return r;
}
static __device__ __forceinline__ void pl32_swap(unsigned& x, unsigned& y) {
  asm("v_permlane32_swap_b32 %0, %1" : "+v"(x), "+v"(y));
}
static __device__ __forceinline__ float fexp2(float x) {   // single v_exp_f32
  float r;
  asm("v_exp_f32 %0, %1" : "=v"(r) : "v"(x));
  return r;
}

// ---------------- cast weights -> bf16 + rope cos/sin table ---------------
// x is NOT cast here anymore (fused into gemm1's A staging).
// Segments (4-elem groups): wq [0,262144) wk [..278528) wv [..294912)
// wo [..557056, norm_w folded); rope table entries [557056, 622592).
__global__ __launch_bounds__(256) void cast_w_kernel(const float* __restrict__ wq,
                                                     const float* __restrict__ wk,
                                                     const float* __restrict__ wv,
                                                     const float* __restrict__ wo,
                                                     const float* __restrict__ nw,
                                                     bf16* __restrict__ wqkv,
                                                     bf16* __restrict__ wob,
                                                     float2* __restrict__ tbl) {
  int i = blockIdx.x * blockDim.x + threadIdx.x;
  if (i >= 557056) {                    // rope table: one (s, i) per thread
    int idx = i - 557056;               // 0..65535
    int s2 = idx >> 5, i2 = idx & 31;
    float fr = expf(-(float)i2 * (9.210340371976184f / 32.0f)); // theta^(-i/32)
    float sn, cs;
    sincosf((float)s2 * fr, &sn, &cs);
    tbl[idx] = make_float2(cs, sn);
    return;
  }
  if (i >= 294912) {                    // Wo segment (with norm_w fold)
    int j = i - 294912;
    const float* s = wo + (size_t)j * 4;
    bf16* d = wob + (size_t)j * 4;
    int d0 = (j * 4) & 1023;
    float4 v = *(const float4*)s;
    float4 g = *(const float4*)(nw + d0);
    d[0] = __float2bfloat16(v.x * g.x);
    d[1] = __float2bfloat16(v.y * g.y);
    d[2] = __float2bfloat16(v.z * g.z);
    d[3] = __float2bfloat16(v.w * g.w);
    return;
  }
  const float* s;
  bf16* d;
  if (i < 262144)       { s = wq + (size_t)i * 4;                d = wqkv + (size_t)i * 4; }
  else if (i < 278528)  { int j = i - 262144; s = wk + (size_t)j * 4; d = wqkv + (size_t)1024 * 1024 + (size_t)j * 4; }
  else                  { int j = i - 278528; s = wv + (size_t)j * 4; d = wqkv + (size_t)1088 * 1024 + (size_t)j * 4; }
  float4 v = *(const float4*)s;
  d[0] = __float2bfloat16(v.x);
  d[1] = __float2bfloat16(v.y);
  d[2] = __float2bfloat16(v.z);
  d[3] = __float2bfloat16(v.w);
}

// ---------------- bf16 GEMM: C[M][N] = A[M][K] * B[N][K]^T ----------------
// Tile 128x64, BK=64, single-buffer LDS, 2-D-chunked XCD swizzle (r20 best).
// MODE 1: A is fp32 (raw x) — staged via reg-load + v_cvt_pk_bf16 + ds_write
//   (fuses the x cast; kills the 25MB cast round-trip). Epilogue: fused RoPE
//   + fragment-major repack (no C write).
// MODE 2: A is bf16 (Nb) — global_load_lds staging; fused rmsnorm row-scale.
template <int MODE>
__global__ __launch_bounds__(256) void gemm_bt(const void* __restrict__ Ap,
                                               const bf16* __restrict__ Bm,
                                               float* __restrict__ C,
                                               const float* __restrict__ ssq,
                                               bf16* __restrict__ QF,
                                               bf16* __restrict__ KF,
                                               bf16* __restrict__ VF,
                                               const float2* __restrict__ tbl,
                                               int M, int N, int K) {
  __shared__ bf16 lA[128 * 64];
  __shared__ bf16 lB[64 * 64];
  __shared__ float rms_l[128];
  const int tid = threadIdx.x;
  const int w = tid >> 6, l = tid & 63;
  const int lg = l >> 4, ln = l & 15;
  const int wr = w >> 1, wc = w & 1;

  // 2-D-chunked XCD swizzle (nm == 32 at both call sites; nwg % 8 == 0)
  const int xcd = blockIdx.x & 7;
  const int loc = blockIdx.x >> 3;
  const int bx  = xcd * 4 + (loc & 3);
  const int by  = loc >> 2;
  const int m0 = bx * 128, n0 = by * 64;

  if (MODE == 2 && tid < 128) {
    const float4* s4 = (const float4*)(ssq + (size_t)(m0 + tid) * 16);
    float4 a = s4[0], b = s4[1], c = s4[2], d = s4[3];
    float tot = (a.x + a.y + a.z + a.w) + (b.x + b.y + b.z + b.w) +
                (c.x + c.y + c.z + c.w) + (d.x + d.y + d.z + d.w);
    rms_l[tid] = rsqrtf(tot * (1.0f / 1024.0f) + 1e-6f);
  }

  f32x4 acc[4][2] = {};

  for (int k0 = 0; k0 < K; k0 += 64) {
    if (MODE == 1) {
      // A: fp32 source, cast-in-flight to bf16 LDS
      const float* Af = (const float*)Ap;
#pragma unroll
      for (int it = 0; it < 4; ++it) {
        int c = tid + it * 256;
        int row = c >> 3, col = (c & 7) * 8;
        const float4* src = (const float4*)(Af + (size_t)(m0 + row) * K + k0 + col);
        float4 v0 = src[0], v1 = src[1];
        u32x4 pk = { cvt_pk_bf16(v0.x, v0.y), cvt_pk_bf16(v0.z, v0.w),
                     cvt_pk_bf16(v1.x, v1.y), cvt_pk_bf16(v1.z, v1.w) };
        *(u32x4*)(&lA[c * 8]) = pk;
      }
    } else {
      const bf16* Ab = (const bf16*)Ap;
#pragma unroll
      for (int it = 0; it < 4; ++it) {
        int c = tid + it * 256;
        int row = c >> 3, col = (c & 7) * 8;
        __builtin_amdgcn_global_load_lds(
            (const __attribute__((address_space(1))) void*)(Ab + (size_t)(m0 + row) * K + k0 + col),
            (__attribute__((address_space(3))) void*)(&lA[c * 8]), 16, 0, 0);
      }
    }
#pragma unroll
    for (int it = 0; it < 2; ++it) {
      int c = tid + it * 256;
      int row = c >> 3, col = (c & 7) * 8;
      __builtin_amdgcn_global_load_lds(
          (const __attribute__((address_space(1))) void*)(Bm + (size_t)(n0 + row) * K + k0 + col),
          (__attribute__((address_space(3))) void*)(&lB[c * 8]), 16, 0, 0);
    }
    __syncthreads();
    for (int ks = 0; ks < 2; ++ks) {
      s16x8 af[4], bfr[2];
      for (int m = 0; m < 4; ++m)
        af[m] = *(const s16x8*)(&lA[(wr * 64 + m * 16 + ln) * 64 + ks * 32 + lg * 8]);
      for (int n = 0; n < 2; ++n)
        bfr[n] = *(const s16x8*)(&lB[(wc * 32 + n * 16 + ln) * 64 + ks * 32 + lg * 8]);
      for (int m = 0; m < 4; ++m)
        for (int n = 0; n < 2; ++n)
          acc[m][n] = __builtin_amdgcn_mfma_f32_16x16x32_bf16(af[m], bfr[n], acc[m][n], 0, 0, 0);
    }
    __syncthreads();
  }

  if (MODE == 1) {
#pragma unroll
    for (int m = 0; m < 4; ++m)
#pragma unroll
      for (int r = 0; r < 4; ++r) {
        int row = m0 + wr * 64 + m * 16 + lg * 4 + r;
        int b2 = row >> 11, s2 = row & 2047;
        int qt = s2 >> 5, ql2 = s2 & 31;
#pragma unroll
        for (int n = 0; n < 2; ++n) {
          float v = acc[m][n][r];
          int f = wc * 32 + n * 16 + ln;          // head-dim 0..63
          if (by < 17) {                          // Q or K: rotate
            float p = __shfl_xor(v, 1);
            float2 cs2 = tbl[(size_t)s2 * 32 + (f >> 1)];
            float rot = (ln & 1) ? fmaf(p, cs2.y, v * cs2.x)
                                 : fmaf(v, cs2.x, -p * cs2.y);
            int ks2 = f >> 4, hi2 = (f >> 3) & 1, j2 = f & 7;
            if (by < 16)
              QF[(((((size_t)b2 * NH + by) * 64 + qt) * 4 + ks2) * 64 + hi2 * 32 + ql2) * 8 + j2] =
                  __float2bfloat16(rot * QSCL);
            else
              KF[((((size_t)b2 * 64 + qt) * 4 + ks2) * 64 + hi2 * 32 + ql2) * 8 + j2] =
                  __float2bfloat16(rot);
          } else {                                // V: repack only
            int c2 = (s2 >> 4) & 1, hv = (s2 >> 3) & 1, jv = s2 & 7, dt = f >> 5;
            VF[(((((size_t)b2 * 64 + qt) * 2 + c2) * 2 + dt) * 64 + hv * 32 + (f & 31)) * 8 + jv] =
                __float2bfloat16(v);
          }
        }
      }
  } else {
    for (int m = 0; m < 4; ++m)
      for (int r = 0; r < 4; ++r) {
        int lrow = wr * 64 + m * 16 + lg * 4 + r;
        int grow = m0 + lrow;
        float sc = rms_l[lrow];
        for (int n = 0; n < 2; ++n)
          C[(size_t)grow * N + n0 + wc * 32 + n * 16 + ln] = acc[m][n][r] * sc;
      }
  }
}

// ---------------- Flash attention v16 (unchanged from r19/r20 best) --------
// CU-balanced 1024-block grid, 2 heads/wave KV-shared, 4-wave split-KV,
// no-max softmax, 1-ahead K prefetch, no setprio, asm exp2, fused rmsnorm.
__global__ __launch_bounds__(256, 2) void attn16_kernel(const bf16* __restrict__ QF,
                                                        const bf16* __restrict__ KF,
                                                        const bf16* __restrict__ VF,
                                                        bf16* __restrict__ Nb,
                                                        float* __restrict__ ssq) {
  __shared__ float cb[2][64][66];
  const int bid = blockIdx.x;
  const int qt = (bid < 512) ? (bid >> 4) : 63 - ((bid - 512) >> 4);
  const int hp = (bid >> 1) & 7;
  const int b  = bid & 1;
  const int w  = threadIdx.x >> 6;      // wave 0..3 (kv-split)
  const int l  = threadIdx.x & 63;
  const int ql = l & 31, hi = l >> 5;
  const int h0 = hp * 2, h1 = hp * 2 + 1;

  const bf16* qp0 = QF + ((size_t)((b * NH + h0) * 64 + qt) * 256 + l) * 8;
  const bf16* qp1 = QF + ((size_t)((b * NH + h1) * 64 + qt) * 256 + l) * 8;
  s16x8 qf0[4], qf1[4];
#pragma unroll
  for (int ks = 0; ks < 4; ++ks) {
    qf0[ks] = *(const s16x8*)(qp0 + ks * 512);
    qf1[ks] = *(const s16x8*)(qp1 + ks * 512);
  }

  const bf16* kp = KF + ((size_t)(b * 64 + w) * 256 + l) * 8;
  const bf16* vp = VF + ((size_t)(b * 64 + w) * 256 + l) * 8;

  f32x16 ot0[2] = {}, ot1[2] = {};
  float ls0 = 0.f, ls1 = 0.f;

  auto loadK = [&](s16x8 (&kf)[4]) {
#pragma unroll
    for (int ks = 0; ks < 4; ++ks) kf[ks] = *(const s16x8*)(kp + ks * 512);
    kp += 4 * 2048;                     // 4 tiles x 2048 elems
  };

  auto softmax_pv = [&](const f32x16& sa, const f32x16& sb, bool diag,
                        float& ls, f32x16 (&ot)[2], s16x8 (&vf)[4]) {
    float p[16];
    if (diag) {
#pragma unroll
      for (int r = 0; r < 16; ++r) {
        const int cr = (r & 3) + 8 * (r >> 2);
        p[r] = (cr + 4 * hi > ql) ? 0.f : fexp2(sa[r] + sb[r]);
      }
    } else {
#pragma unroll
      for (int r = 0; r < 16; ++r) p[r] = fexp2(sa[r] + sb[r]);
    }
    float t8[8];
#pragma unroll
    for (int r = 0; r < 8; ++r) t8[r] = p[2 * r] + p[2 * r + 1];
#pragma unroll
    for (int r = 0; r < 4; ++r) t8[r] = t8[r] + t8[r + 4];
    float rs = (t8[0] + t8[2]) + (t8[1] + t8[3]);
    rs += __shfl_xor(rs, 32);
    ls += rs;
#pragma unroll
    for (int c = 0; c < 2; ++c) {
      unsigned w0 = cvt_pk_bf16(p[c * 8 + 0], p[c * 8 + 1]);
      unsigned w2 = cvt_pk_bf16(p[c * 8 + 4], p[c * 8 + 5]);
      unsigned w1 = cvt_pk_bf16(p[c * 8 + 2], p[c * 8 + 3]);
      unsigned w3 = cvt_pk_bf16(p[c * 8 + 6], p[c * 8 + 7]);
      pl32_swap(w0, w2);
      pl32_swap(w1, w3);
      u32x4 pu = {w0, w1, w2, w3};
      s16x8 pb = *(s16x8*)&pu;
#pragma unroll
      for (int dt = 0; dt < 2; ++dt)
        ot[dt] = __builtin_amdgcn_mfma_f32_32x32x16_bf16(vf[c * 2 + dt], pb, ot[dt], 0, 0, 0);
    }
  };

  auto compute = [&](int t, s16x8 (&kf)[4]) {
    s16x8 vf[4];
#pragma unroll
    for (int j = 0; j < 4; ++j) vf[j] = *(const s16x8*)(vp + j * 512);
    vp += 4 * 2048;
    const bool diag = (t == qt);
    f32x16 s0a = {}, s0b = {}, s1a = {}, s1b = {};
    s0a = __builtin_amdgcn_mfma_f32_32x32x16_bf16(kf[0], qf0[0], s0a, 0, 0, 0);
    s1a = __builtin_amdgcn_mfma_f32_32x32x16_bf16(kf[0], qf1[0], s1a, 0, 0, 0);
    s0b = __builtin_amdgcn_mfma_f32_32x32x16_bf16(kf[2], qf0[2], s0b, 0, 0, 0);
    s1b = __builtin_amdgcn_mfma_f32_32x32x16_bf16(kf[2], qf1[2], s1b, 0, 0, 0);
    s0a = __builtin_amdgcn_mfma_f32_32x32x16_bf16(kf[1], qf0[1], s0a, 0, 0, 0);
    s1a = __builtin_amdgcn_mfma_f32_32x32x16_bf16(kf[1], qf1[1], s1a, 0, 0, 0);
    s0b = __builtin_amdgcn_mfma_f32_32x32x16_bf16(kf[3], qf0[3], s0b, 0, 0, 0);
    s1b = __builtin_amdgcn_mfma_f32_32x32x16_bf16(kf[3], qf1[3], s1b, 0, 0, 0);
    softmax_pv(s0a, s0b, diag, ls0, ot0, vf);
    softmax_pv(s1a, s1b, diag, ls1, ot1, vf);
  };

  // main loop: K prefetched 1 tile ahead (named buffers), V in compute
  s16x8 kA[4], kB[4];
  int t = w;
  if (t <= qt) {
    loadK(kA);
    while (true) {
      if (t + 4 <= qt) loadK(kB);
      compute(t, kA);
      t += 4;
      if (t > qt) break;
      if (t + 4 <= qt) loadK(kA);
      compute(t, kB);
      t += 4;
      if (t > qt) break;
    }
  }

  // ---- LDS tree combine (pure sums, both heads) ----
  auto dumpLDS = [&](int slot) {
    float* dst = &cb[slot][l][0];
#pragma unroll
    for (int r = 0; r < 16; ++r) {
      dst[r]      = ot0[0][r];
      dst[16 + r] = ot0[1][r];
      dst[32 + r] = ot1[0][r];
      dst[48 + r] = ot1[1][r];
    }
    dst[64] = ls0; dst[65] = ls1;
  };
  auto mergeLDS = [&](int slot) {
    const float* src = &cb[slot][l][0];
#pragma unroll
    for (int r = 0; r < 16; ++r) {
      ot0[0][r] += src[r];
      ot0[1][r] += src[16 + r];
      ot1[0][r] += src[32 + r];
      ot1[1][r] += src[48 + r];
    }
    ls0 += src[64]; ls1 += src[65];
  };

  if (w == 1) dumpLDS(0);
  if (w == 3) dumpLDS(1);
  __syncthreads();
  if (w == 0) mergeLDS(0);
  if (w == 2) mergeLDS(1);
  __syncthreads();
  if (w == 2) dumpLDS(0);
  __syncthreads();
  if (w == 0) {
    mergeLDS(0);
    const int rowg = b * SEQ + qt * 32 + ql;
    {
      float inv = 1.0f / ls0;
      float sq = 0.f;
      bf16* nb = Nb + (size_t)rowg * DIMC + h0 * HD;
#pragma unroll
      for (int dt = 0; dt < 2; ++dt)
#pragma unroll
        for (int rq = 0; rq < 4; ++rq) {
          float o0 = ot0[dt][4 * rq + 0] * inv, o1 = ot0[dt][4 * rq + 1] * inv;
          float o2 = ot0[dt][4 * rq + 2] * inv, o3 = ot0[dt][4 * rq + 3] * inv;
          sq += o0 * o0 + o1 * o1 + o2 * o2 + o3 * o3;
          uint2 pk = { cvt_pk_bf16(o0, o1), cvt_pk_bf16(o2, o3) };
          *(uint2*)(nb + dt * 32 + rq * 8 + 4 * hi) = pk;
        }
      sq += __shfl_xor(sq, 32);
      if (hi == 0) ssq[rowg * 16 + h0] = sq;
    }
    {
      float inv = 1.0f / ls1;
      float sq = 0.f;
      bf16* nb = Nb + (size_t)rowg * DIMC + h1 * HD;
#pragma unroll
      for (int dt = 0; dt < 2; ++dt)
#pragma unroll
        for (int rq = 0; rq < 4; ++rq) {
          float o0 = ot1[dt][4 * rq + 0] * inv, o1 = ot1[dt][4 * rq + 1] * inv;
          float o2 = ot1[dt][4 * rq + 2] * inv, o3 = ot1[dt][4 * rq + 3] * inv;
          sq += o0 * o0 + o1 * o1 + o2 * o2 + o3 * o3;
          uint2 pk = { cvt_pk_bf16(o0, o1), cvt_pk_bf16(o2, o3) };
          *(uint2*)(nb + dt * 32 + rq * 8 + 4 * hi) = pk;
        }
      sq += __shfl_xor(sq, 32);
      if (hi == 0) ssq[rowg * 16 + h1] = sq;
    }
  }
}

// ---------------- launch ----------------
extern "C" void kernel_launch(void* const* d_in, const int* in_sizes, int n_in,
                              void* d_out, int out_size, void* d_ws, size_t ws_size,
                              hipStream_t stream) {
  const float* x      = (const float*)d_in[0];
  const float* Wq     = (const float*)d_in[1];
  const float* Wk     = (const float*)d_in[2];
  const float* Wv     = (const float*)d_in[3];
  const float* Wo     = (const float*)d_in[4];
  const float* norm_w = (const float*)d_in[5];

  size_t off = 0;
  auto alloc = [&](size_t bytes) {
    void* p = (char*)d_ws + off;
    off += (bytes + 255) & ~(size_t)255;
    return p;
  };
  bf16*   Wqkv = (bf16*)alloc((size_t)NQKV * DIMC * 2);
  bf16*   Wob  = (bf16*)alloc((size_t)DIMC * DIMC * 2);
  bf16*   QF   = (bf16*)alloc((size_t)NB * NH * 64 * 4 * 64 * 8 * 2);   // 8 MB
  bf16*   KF   = (bf16*)alloc((size_t)NB * 64 * 4 * 64 * 8 * 2);        // 1 MB
  bf16*   VF   = (bf16*)alloc((size_t)NB * 64 * 4 * 64 * 8 * 2);        // 1 MB
  bf16*   Nb   = (bf16*)alloc((size_t)NROWS * DIMC * 2);
  float*  ssq  = (float*)alloc((size_t)NROWS * 16 * 4);
  float2* tbl  = (float2*)alloc((size_t)SEQ * 32 * 8);                  // 512 KB

  // weight casts (norm_w folded into Wo) + rope table build
  cast_w_kernel<<<2432, 256, 0, stream>>>(Wq, Wk, Wv, Wo, norm_w,
                                          Wqkv, Wob, tbl);

  // QKV projection reading raw fp32 x (cast fused into A staging),
  // FUSED RoPE + fragment-major repack epilogue (2-D XCD swizzle)
  gemm_bt<1><<<(NROWS / 128) * (NQKV / 64), 256, 0, stream>>>(
      x, Wqkv, nullptr, nullptr, QF, KF, VF, tbl, NROWS, NQKV, DIMC);

  // attention v16 (no setprio, asm exp2, CU-balanced grid)
  attn16_kernel<<<1024, 256, 0, stream>>>(QF, KF, VF, Nb, ssq);

  // output projection with fused rms (2-D XCD swizzle)
  gemm_bt<2><<<(NROWS / 128) * (DIMC / 64), 256, 0, stream>>>(
      Nb, Wob, (float*)d_out, ssq, nullptr, nullptr, nullptr, nullptr,
      NROWS, DIMC, DIMC);
}

// Round 22
// 89.823 us; speedup vs baseline: 1.1955x; 1.1955x over previous
//
#include <hip/hip_runtime.h>
#include <hip/hip_bf16.h>

typedef __attribute__((ext_vector_type(4)))  float f32x4;
typedef __attribute__((ext_vector_type(16))) float f32x16;
typedef __attribute__((ext_vector_type(8)))  short s16x8;
typedef __attribute__((ext_vector_type(4)))  unsigned int u32x4;

using bf16 = __hip_bfloat16;

#define DIMC   1024
#define NH     16
#define HD     64
#define SEQ    2048
#define NB     2
#define NROWS  (NB*SEQ)   // 4096
#define NQKV   1152       // 1024 q + 64 k + 64 v
#define QSCL   0.18033688f   // 1/sqrt(64) * log2(e), folded into Q at epilogue

// ---------------- fused cast fp32 -> bf16 + rope cos/sin table ------------
__global__ __launch_bounds__(256) void cast_all_kernel(const float* __restrict__ x,
                                                       const float* __restrict__ wq,
                                                       const float* __restrict__ wk,
                                                       const float* __restrict__ wv,
                                                       const float* __restrict__ wo,
                                                       const float* __restrict__ nw,
                                                       bf16* __restrict__ xbf,
                                                       bf16* __restrict__ wqkv,
                                                       bf16* __restrict__ wob,
                                                       float2* __restrict__ tbl) {
  int i = blockIdx.x * blockDim.x + threadIdx.x;
  if (i >= 1605632) {                   // rope table: one (s, i) per thread
    int idx = i - 1605632;              // 0..65535
    int s2 = idx >> 5, i2 = idx & 31;
    float fr = expf(-(float)i2 * (9.210340371976184f / 32.0f)); // theta^(-i/32)
    float sn, cs;
    sincosf((float)s2 * fr, &sn, &cs);
    tbl[idx] = make_float2(cs, sn);
    return;
  }
  if (i >= 1343488) {                   // Wo segment (with norm_w fold)
    int j = i - 1343488;
    const float* s = wo + (size_t)j * 4;
    bf16* d = wob + (size_t)j * 4;
    int d0 = (j * 4) & 1023;
    float4 v = *(const float4*)s;
    float4 g = *(const float4*)(nw + d0);
    d[0] = __float2bfloat16(v.x * g.x);
    d[1] = __float2bfloat16(v.y * g.y);
    d[2] = __float2bfloat16(v.z * g.z);
    d[3] = __float2bfloat16(v.w * g.w);
    return;
  }
  const float* s;
  bf16* d;
  if (i < 1048576)      { s = x  + (size_t)i * 4;                 d = xbf + (size_t)i * 4; }
  else if (i < 1310720) { int j = i - 1048576; s = wq + (size_t)j * 4; d = wqkv + (size_t)j * 4; }
  else if (i < 1327104) { int j = i - 1310720; s = wk + (size_t)j * 4; d = wqkv + (size_t)1024 * 1024 + (size_t)j * 4; }
  else                  { int j = i - 1327104; s = wv + (size_t)j * 4; d = wqkv + (size_t)1088 * 1024 + (size_t)j * 4; }
  float4 v = *(const float4*)s;
  d[0] = __float2bfloat16(v.x);
  d[1] = __float2bfloat16(v.y);
  d[2] = __float2bfloat16(v.z);
  d[3] = __float2bfloat16(v.w);
}

// ---------------- bf16 GEMM: C[M][N] = A[M][K] * B[N][K]^T ----------------
// Tile 128x64, BK=64, single-buffer LDS. 1-D grid with 2-D-chunked XCD
// swizzle: each XCD's chunk covers bx in [xcd*4, xcd*4+4) x ALL by -> its L2
// holds both the A slice (1MB) and all B panels (~2.25MB).
// MODE 1: QKV projection + fused RoPE/fragment-repack epilogue (no C write).
// MODE 2: output projection + fused rmsnorm row-scale (from ssq), fp32 C.
template <int MODE>
__global__ __launch_bounds__(256) void gemm_bt(const bf16* __restrict__ A,
                                               const bf16* __restrict__ Bm,
                                               float* __restrict__ C,
                                               const float* __restrict__ ssq,
                                               bf16* __restrict__ QF,
                                               bf16* __restrict__ KF,
                                               bf16* __restrict__ VF,
                                               const float2* __restrict__ tbl,
                                               int M, int N, int K) {
  __shared__ bf16 lA[128 * 64];
  __shared__ bf16 lB[64 * 64];
  __shared__ float rms_l[128];
  const int tid = threadIdx.x;
  const int w = tid >> 6, l = tid & 63;
  const int lg = l >> 4, ln = l & 15;
  const int wr = w >> 1, wc = w & 1;

  // 2-D-chunked XCD swizzle (nm == 32 at both call sites; nwg % 8 == 0)
  const int xcd = blockIdx.x & 7;
  const int loc = blockIdx.x >> 3;      // 0 .. nwg/8-1
  const int bx  = xcd * 4 + (loc & 3);  // 4 bx values per XCD
  const int by  = loc >> 2;             // all by values per XCD
  const int m0 = bx * 128, n0 = by * 64;

  if (MODE == 2 && tid < 128) {
    const float4* s4 = (const float4*)(ssq + (size_t)(m0 + tid) * 16);
    float4 a = s4[0], b = s4[1], c = s4[2], d = s4[3];
    float tot = (a.x + a.y + a.z + a.w) + (b.x + b.y + b.z + b.w) +
                (c.x + c.y + c.z + c.w) + (d.x + d.y + d.z + d.w);
    rms_l[tid] = rsqrtf(tot * (1.0f / 1024.0f) + 1e-6f);
  }

  f32x4 acc[4][2] = {};

  for (int k0 = 0; k0 < K; k0 += 64) {
#pragma unroll
    for (int it = 0; it < 4; ++it) {
      int c = tid + it * 256;
      int row = c >> 3, col = (c & 7) * 8;
      __builtin_amdgcn_global_load_lds(
          (const __attribute__((address_space(1))) void*)(A + (size_t)(m0 + row) * K + k0 + col),
          (__attribute__((address_space(3))) void*)(&lA[c * 8]), 16, 0, 0);
    }
#pragma unroll
    for (int it = 0; it < 2; ++it) {
      int c = tid + it * 256;
      int row = c >> 3, col = (c & 7) * 8;
      __builtin_amdgcn_global_load_lds(
          (const __attribute__((address_space(1))) void*)(Bm + (size_t)(n0 + row) * K + k0 + col),
          (__attribute__((address_space(3))) void*)(&lB[c * 8]), 16, 0, 0);
    }
    __syncthreads();
    for (int ks = 0; ks < 2; ++ks) {
      s16x8 af[4], bfr[2];
      for (int m = 0; m < 4; ++m)
        af[m] = *(const s16x8*)(&lA[(wr * 64 + m * 16 + ln) * 64 + ks * 32 + lg * 8]);
      for (int n = 0; n < 2; ++n)
        bfr[n] = *(const s16x8*)(&lB[(wc * 32 + n * 16 + ln) * 64 + ks * 32 + lg * 8]);
      for (int m = 0; m < 4; ++m)
        for (int n = 0; n < 2; ++n)
          acc[m][n] = __builtin_amdgcn_mfma_f32_16x16x32_bf16(af[m], bfr[n], acc[m][n], 0, 0, 0);
    }
    __syncthreads();
  }

  if (MODE == 1) {
#pragma unroll
    for (int m = 0; m < 4; ++m)
#pragma unroll
      for (int r = 0; r < 4; ++r) {
        int row = m0 + wr * 64 + m * 16 + lg * 4 + r;
        int b2 = row >> 11, s2 = row & 2047;
        int qt = s2 >> 5, ql2 = s2 & 31;
#pragma unroll
        for (int n = 0; n < 2; ++n) {
          float v = acc[m][n][r];
          int f = wc * 32 + n * 16 + ln;          // head-dim 0..63
          if (by < 17) {                          // Q or K: rotate
            float p = __shfl_xor(v, 1);
            float2 cs2 = tbl[(size_t)s2 * 32 + (f >> 1)];
            float rot = (ln & 1) ? fmaf(p, cs2.y, v * cs2.x)
                                 : fmaf(v, cs2.x, -p * cs2.y);
            int ks2 = f >> 4, hi2 = (f >> 3) & 1, j2 = f & 7;
            if (by < 16)
              QF[(((((size_t)b2 * NH + by) * 64 + qt) * 4 + ks2) * 64 + hi2 * 32 + ql2) * 8 + j2] =
                  __float2bfloat16(rot * QSCL);
            else
              KF[((((size_t)b2 * 64 + qt) * 4 + ks2) * 64 + hi2 * 32 + ql2) * 8 + j2] =
                  __float2bfloat16(rot);
          } else {                                // V: repack only
            int c2 = (s2 >> 4) & 1, hv = (s2 >> 3) & 1, jv = s2 & 7, dt = f >> 5;
            VF[(((((size_t)b2 * 64 + qt) * 2 + c2) * 2 + dt) * 64 + hv * 32 + (f & 31)) * 8 + jv] =
                __float2bfloat16(v);
          }
        }
      }
  } else {
    for (int m = 0; m < 4; ++m)
      for (int r = 0; r < 4; ++r) {
        int lrow = wr * 64 + m * 16 + lg * 4 + r;
        int grow = m0 + lrow;
        float sc = rms_l[lrow];
        for (int n = 0; n < 2; ++n)
          C[(size_t)grow * N + n0 + wc * 32 + n * 16 + ln] = acc[m][n][r] * sc;
      }
  }
}

// ---- cross-lane / fast-math helpers (gfx950) ----
static __device__ __forceinline__ unsigned cvt_pk_bf16(float lo, float hi) {
  unsigned r;
  asm("v_cvt_pk_bf16_f32 %0, %1, %2" : "=v"(r) : "v"(lo), "v"(hi));
  return r;
}
static __device__ __forceinline__ void pl32_swap(unsigned& x, unsigned& y) {
  asm("v_permlane32_swap_b32 %0, %1" : "+v"(x), "+v"(y));
}
static __device__ __forceinline__ float fexp2(float x) {   // single v_exp_f32
  float r;
  asm("v_exp_f32 %0, %1" : "=v"(r) : "v"(x));
  return r;
}

// ---------------- Flash attention v16 (r19/r20 best) -----------------------
// CU-balanced 1024-block grid, 2 heads/wave KV-shared, 4-wave split-KV,
// no-max softmax, 1-ahead K prefetch, no setprio, asm exp2, fused rmsnorm.
__global__ __launch_bounds__(256, 2) void attn16_kernel(const bf16* __restrict__ QF,
                                                        const bf16* __restrict__ KF,
                                                        const bf16* __restrict__ VF,
                                                        bf16* __restrict__ Nb,
                                                        float* __restrict__ ssq) {
  __shared__ float cb[2][64][66];
  const int bid = blockIdx.x;
  const int qt = (bid < 512) ? (bid >> 4) : 63 - ((bid - 512) >> 4);
  const int hp = (bid >> 1) & 7;
  const int b  = bid & 1;
  const int w  = threadIdx.x >> 6;      // wave 0..3 (kv-split)
  const int l  = threadIdx.x & 63;
  const int ql = l & 31, hi = l >> 5;
  const int h0 = hp * 2, h1 = hp * 2 + 1;

  const bf16* qp0 = QF + ((size_t)((b * NH + h0) * 64 + qt) * 256 + l) * 8;
  const bf16* qp1 = QF + ((size_t)((b * NH + h1) * 64 + qt) * 256 + l) * 8;
  s16x8 qf0[4], qf1[4];
#pragma unroll
  for (int ks = 0; ks < 4; ++ks) {
    qf0[ks] = *(const s16x8*)(qp0 + ks * 512);
    qf1[ks] = *(const s16x8*)(qp1 + ks * 512);
  }

  const bf16* kp = KF + ((size_t)(b * 64 + w) * 256 + l) * 8;
  const bf16* vp = VF + ((size_t)(b * 64 + w) * 256 + l) * 8;

  f32x16 ot0[2] = {}, ot1[2] = {};
  float ls0 = 0.f, ls1 = 0.f;

  auto loadK = [&](s16x8 (&kf)[4]) {
#pragma unroll
    for (int ks = 0; ks < 4; ++ks) kf[ks] = *(const s16x8*)(kp + ks * 512);
    kp += 4 * 2048;                     // 4 tiles x 2048 elems
  };

  auto softmax_pv = [&](const f32x16& sa, const f32x16& sb, bool diag,
                        float& ls, f32x16 (&ot)[2], s16x8 (&vf)[4]) {
    float p[16];
    if (diag) {
#pragma unroll
      for (int r = 0; r < 16; ++r) {
        const int cr = (r & 3) + 8 * (r >> 2);
        p[r] = (cr + 4 * hi > ql) ? 0.f : fexp2(sa[r] + sb[r]);
      }
    } else {
#pragma unroll
      for (int r = 0; r < 16; ++r) p[r] = fexp2(sa[r] + sb[r]);
    }
    float t8[8];
#pragma unroll
    for (int r = 0; r < 8; ++r) t8[r] = p[2 * r] + p[2 * r + 1];
#pragma unroll
    for (int r = 0; r < 4; ++r) t8[r] = t8[r] + t8[r + 4];
    float rs = (t8[0] + t8[2]) + (t8[1] + t8[3]);
    rs += __shfl_xor(rs, 32);
    ls += rs;
#pragma unroll
    for (int c = 0; c < 2; ++c) {
      unsigned w0 = cvt_pk_bf16(p[c * 8 + 0], p[c * 8 + 1]);
      unsigned w2 = cvt_pk_bf16(p[c * 8 + 4], p[c * 8 + 5]);
      unsigned w1 = cvt_pk_bf16(p[c * 8 + 2], p[c * 8 + 3]);
      unsigned w3 = cvt_pk_bf16(p[c * 8 + 6], p[c * 8 + 7]);
      pl32_swap(w0, w2);
      pl32_swap(w1, w3);
      u32x4 pu = {w0, w1, w2, w3};
      s16x8 pb = *(s16x8*)&pu;
#pragma unroll
      for (int dt = 0; dt < 2; ++dt)
        ot[dt] = __builtin_amdgcn_mfma_f32_32x32x16_bf16(vf[c * 2 + dt], pb, ot[dt], 0, 0, 0);
    }
  };

  auto compute = [&](int t, s16x8 (&kf)[4]) {
    s16x8 vf[4];
#pragma unroll
    for (int j = 0; j < 4; ++j) vf[j] = *(const s16x8*)(vp + j * 512);
    vp += 4 * 2048;
    const bool diag = (t == qt);
    f32x16 s0a = {}, s0b = {}, s1a = {}, s1b = {};
    s0a = __builtin_amdgcn_mfma_f32_32x32x16_bf16(kf[0], qf0[0], s0a, 0, 0, 0);
    s1a = __builtin_amdgcn_mfma_f32_32x32x16_bf16(kf[0], qf1[0], s1a, 0, 0, 0);
    s0b = __builtin_amdgcn_mfma_f32_32x32x16_bf16(kf[2], qf0[2], s0b, 0, 0, 0);
    s1b = __builtin_amdgcn_mfma_f32_32x32x16_bf16(kf[2], qf1[2], s1b, 0, 0, 0);
    s0a = __builtin_amdgcn_mfma_f32_32x32x16_bf16(kf[1], qf0[1], s0a, 0, 0, 0);
    s1a = __builtin_amdgcn_mfma_f32_32x32x16_bf16(kf[1], qf1[1], s1a, 0, 0, 0);
    s0b = __builtin_amdgcn_mfma_f32_32x32x16_bf16(kf[3], qf0[3], s0b, 0, 0, 0);
    s1b = __builtin_amdgcn_mfma_f32_32x32x16_bf16(kf[3], qf1[3], s1b, 0, 0, 0);
    softmax_pv(s0a, s0b, diag, ls0, ot0, vf);
    softmax_pv(s1a, s1b, diag, ls1, ot1, vf);
  };

  // main loop: K prefetched 1 tile ahead (named buffers), V in compute
  s16x8 kA[4], kB[4];
  int t = w;
  if (t <= qt) {
    loadK(kA);
    while (true) {
      if (t + 4 <= qt) loadK(kB);
      compute(t, kA);
      t += 4;
      if (t > qt) break;
      if (t + 4 <= qt) loadK(kA);
      compute(t, kB);
      t += 4;
      if (t > qt) break;
    }
  }

  // ---- LDS tree combine (pure sums, both heads) ----
  auto dumpLDS = [&](int slot) {
    float* dst = &cb[slot][l][0];
#pragma unroll
    for (int r = 0; r < 16; ++r) {
      dst[r]      = ot0[0][r];
      dst[16 + r] = ot0[1][r];
      dst[32 + r] = ot1[0][r];
      dst[48 + r] = ot1[1][r];
    }
    dst[64] = ls0; dst[65] = ls1;
  };
  auto mergeLDS = [&](int slot) {
    const float* src = &cb[slot][l][0];
#pragma unroll
    for (int r = 0; r < 16; ++r) {
      ot0[0][r] += src[r];
      ot0[1][r] += src[16 + r];
      ot1[0][r] += src[32 + r];
      ot1[1][r] += src[48 + r];
    }
    ls0 += src[64]; ls1 += src[65];
  };

  if (w == 1) dumpLDS(0);
  if (w == 3) dumpLDS(1);
  __syncthreads();
  if (w == 0) mergeLDS(0);
  if (w == 2) mergeLDS(1);
  __syncthreads();
  if (w == 2) dumpLDS(0);
  __syncthreads();
  if (w == 0) {
    mergeLDS(0);
    const int rowg = b * SEQ + qt * 32 + ql;
    {
      float inv = 1.0f / ls0;
      float sq = 0.f;
      bf16* nb = Nb + (size_t)rowg * DIMC + h0 * HD;
#pragma unroll
      for (int dt = 0; dt < 2; ++dt)
#pragma unroll
        for (int rq = 0; rq < 4; ++rq) {
          float o0 = ot0[dt][4 * rq + 0] * inv, o1 = ot0[dt][4 * rq + 1] * inv;
          float o2 = ot0[dt][4 * rq + 2] * inv, o3 = ot0[dt][4 * rq + 3] * inv;
          sq += o0 * o0 + o1 * o1 + o2 * o2 + o3 * o3;
          uint2 pk = { cvt_pk_bf16(o0, o1), cvt_pk_bf16(o2, o3) };
          *(uint2*)(nb + dt * 32 + rq * 8 + 4 * hi) = pk;
        }
      sq += __shfl_xor(sq, 32);
      if (hi == 0) ssq[rowg * 16 + h0] = sq;
    }
    {
      float inv = 1.0f / ls1;
      float sq = 0.f;
      bf16* nb = Nb + (size_t)rowg * DIMC + h1 * HD;
#pragma unroll
      for (int dt = 0; dt < 2; ++dt)
#pragma unroll
        for (int rq = 0; rq < 4; ++rq) {
          float o0 = ot1[dt][4 * rq + 0] * inv, o1 = ot1[dt][4 * rq + 1] * inv;
          float o2 = ot1[dt][4 * rq + 2] * inv, o3 = ot1[dt][4 * rq + 3] * inv;
          sq += o0 * o0 + o1 * o1 + o2 * o2 + o3 * o3;
          uint2 pk = { cvt_pk_bf16(o0, o1), cvt_pk_bf16(o2, o3) };
          *(uint2*)(nb + dt * 32 + rq * 8 + 4 * hi) = pk;
        }
      sq += __shfl_xor(sq, 32);
      if (hi == 0) ssq[rowg * 16 + h1] = sq;
    }
  }
}

// ---------------- launch ----------------
extern "C" void kernel_launch(void* const* d_in, const int* in_sizes, int n_in,
                              void* d_out, int out_size, void* d_ws, size_t ws_size,
                              hipStream_t stream) {
  const float* x      = (const float*)d_in[0];
  const float* Wq     = (const float*)d_in[1];
  const float* Wk     = (const float*)d_in[2];
  const float* Wv     = (const float*)d_in[3];
  const float* Wo     = (const float*)d_in[4];
  const float* norm_w = (const float*)d_in[5];

  size_t off = 0;
  auto alloc = [&](size_t bytes) {
    void* p = (char*)d_ws + off;
    off += (bytes + 255) & ~(size_t)255;
    return p;
  };
  bf16*   Xbf  = (bf16*)alloc((size_t)NROWS * DIMC * 2);
  bf16*   Wqkv = (bf16*)alloc((size_t)NQKV * DIMC * 2);
  bf16*   Wob  = (bf16*)alloc((size_t)DIMC * DIMC * 2);
  bf16*   QF   = (bf16*)alloc((size_t)NB * NH * 64 * 4 * 64 * 8 * 2);   // 8 MB
  bf16*   KF   = (bf16*)alloc((size_t)NB * 64 * 4 * 64 * 8 * 2);        // 1 MB
  bf16*   VF   = (bf16*)alloc((size_t)NB * 64 * 4 * 64 * 8 * 2);        // 1 MB
  bf16*   Nb   = (bf16*)alloc((size_t)NROWS * DIMC * 2);
  float*  ssq  = (float*)alloc((size_t)NROWS * 16 * 4);
  float2* tbl  = (float2*)alloc((size_t)SEQ * 32 * 8);                  // 512 KB

  // fused input casts (norm_w folded into Wo) + rope table build
  cast_all_kernel<<<6528, 256, 0, stream>>>(x, Wq, Wk, Wv, Wo, norm_w,
                                            Xbf, Wqkv, Wob, tbl);

  // QKV projection with FUSED RoPE + fragment-major repack (2-D XCD swizzle)
  gemm_bt<1><<<(NROWS / 128) * (NQKV / 64), 256, 0, stream>>>(
      Xbf, Wqkv, nullptr, nullptr, QF, KF, VF, tbl, NROWS, NQKV, DIMC);

  // attention v16 (no setprio, asm exp2, CU-balanced grid)
  attn16_kernel<<<1024, 256, 0, stream>>>(QF, KF, VF, Nb, ssq);

  // output projection with fused rms (2-D XCD swizzle)
  gemm_bt<2><<<(NROWS / 128) * (DIMC / 64), 256, 0, stream>>>(
      Nb, Wob, (float*)d_out, ssq, nullptr, nullptr, nullptr, nullptr,
      NROWS, DIMC, DIMC);
}